// Round 8
// baseline (341.682 us; speedup 1.0000x reference)
//
#include <hip/hip_runtime.h>

#define N_NODES 100000
#define N_EDGES 1600000
#define DIM 128
#define NGRAPH 64
#define M_PAD 100096   // 782 * 128 = 1564 * 64
#define NBUCKET 782    // ceil(100000 / 128)
#define BCAP 4096      // staging capacity per bucket (mean 2046, sigma ~45)
#define CHUNK 8192     // edges per scatter block
#define SCAT_B 196     // scatter blocks in k_prep
#define XCV_B 3125     // x-convert blocks in k_prep (12.8M floats / 4096)
#define WCV_B 24       // W-convert blocks in k_prep (98304 / 4096)

typedef __attribute__((ext_vector_type(8))) short bf16x8;
typedef __attribute__((ext_vector_type(4))) float floatx4;
typedef __attribute__((ext_vector_type(2))) float floatx2;

static __device__ __forceinline__ unsigned int f2bf(float f) {
    unsigned int u = __builtin_bit_cast(unsigned int, f);
    return (u + 0x7FFFu + ((u >> 16) & 1u)) >> 16;
}
static __device__ __forceinline__ unsigned int pk_fp8x4(float a, float b, float c, float d) {
    unsigned int r = 0;
    r = __builtin_amdgcn_cvt_pk_fp8_f32(a, b, r, false);
    r = __builtin_amdgcn_cvt_pk_fp8_f32(c, d, r, true);
    return r;
}
// async global->LDS DMA, 16B per lane; lds dest = (wave-uniform) base + lane*16
static __device__ __forceinline__ void gld_lds16(const void* g, void* l) {
    __builtin_amdgcn_global_load_lds(
        (const __attribute__((address_space(1))) unsigned int*)g,
        (__attribute__((address_space(3))) unsigned int*)l, 16, 0, 0);
}

// ---------------- fused prep: edge scatter + x->bf16+fp8 + W transpose + pool zero ----------------

__global__ __launch_bounds__(1024) void k_prep(
    const int* __restrict__ src, const int* __restrict__ dst,
    int* __restrict__ bcur, unsigned int* __restrict__ staging,
    const float* __restrict__ x, unsigned short* __restrict__ xb,
    unsigned char* __restrict__ x8,
    const float* __restrict__ Wl1, const float* __restrict__ Wr1,
    unsigned short* __restrict__ Wt1,
    const float* __restrict__ Wl2, const float* __restrict__ Wr2,
    unsigned short* __restrict__ Wt2,
    const float* __restrict__ Wl3, const float* __restrict__ Wr3,
    unsigned short* __restrict__ Wt3,
    float* __restrict__ pooled, float* __restrict__ gcnt) {
    int b = blockIdx.x;
    int tid = threadIdx.x;
    if (b < SCAT_B) {
        __shared__ int cnt[NBUCKET];
        __shared__ int gbase[NBUCKET];
        __shared__ int pos[NBUCKET];
        int e0 = b * CHUNK;
        for (int i = tid; i < NBUCKET; i += 1024) {
            cnt[i] = 0;
            pos[i] = 0;
        }
        __syncthreads();
        int s[8], d[8];
#pragma unroll
        for (int j = 0; j < 8; j++) {
            int e = e0 + j * 1024 + tid;
            if (e < N_EDGES) {
                s[j] = src[e];
                d[j] = dst[e];
                atomicAdd(&cnt[d[j] >> 7], 1);
            } else {
                d[j] = -1;
            }
        }
        __syncthreads();
        for (int i = tid; i < NBUCKET; i += 1024) {
            int c = cnt[i];
            if (c > 0) gbase[i] = atomicAdd(&bcur[i], c);
        }
        __syncthreads();
#pragma unroll
        for (int j = 0; j < 8; j++) {
            if (d[j] >= 0) {
                int bk = d[j] >> 7;
                int gp = gbase[bk] + atomicAdd(&pos[bk], 1);
                if (gp < BCAP)
                    staging[(size_t)bk * BCAP + gp] =
                        (unsigned int)s[j] | ((unsigned int)(d[j] & 127) << 25);
            }
        }
    } else if (b < SCAT_B + XCV_B) {
        size_t i = ((size_t)(b - SCAT_B) * 1024 + tid) * 4;
        float4 v = *(const float4*)(x + i);
        uint2 o;
        o.x = f2bf(v.x) | (f2bf(v.y) << 16);
        o.y = f2bf(v.z) | (f2bf(v.w) << 16);
        *(uint2*)(xb + i) = o;
        *(unsigned int*)(x8 + i) = pk_fp8x4(v.x, v.y, v.z, v.w);
    } else if (b < SCAT_B + XCV_B + WCV_B) {
        int base = (b - SCAT_B - XCV_B) * 4096 + tid * 4;
#pragma unroll
        for (int j = 0; j < 4; j++) {
            int id = base + j;                 // 0..98303
            int layer = id >> 15;
            int rem = id & 32767;
            int n = rem >> 8, k = rem & 255;
            const float* Wl = layer == 0 ? Wl1 : (layer == 1 ? Wl2 : Wl3);
            const float* Wr = layer == 0 ? Wr1 : (layer == 1 ? Wr2 : Wr3);
            unsigned short* Wt = layer == 0 ? Wt1 : (layer == 1 ? Wt2 : Wt3);
            float v = (k < 128) ? Wl[k * 128 + n] : Wr[(k - 128) * 128 + n];
            Wt[n * 256 + k] = (unsigned short)f2bf(v);
        }
    } else {
        for (int i = tid; i < NGRAPH * DIM; i += 1024) pooled[i] = 0.f;
        if (tid < NGRAPH) gcnt[tid] = 0.f;
    }
}

// ---------------- per-bucket counting sort with self-computed prefix ----------------

__global__ __launch_bounds__(256) void k_bsort(const unsigned int* __restrict__ staging,
                                               const int* __restrict__ bcur,
                                               int* __restrict__ rowptr,
                                               int* __restrict__ col) {
    __shared__ unsigned int lpk[BCAP];
    __shared__ int lcol[BCAP];
    __shared__ int loff[129];
    __shared__ int lcur[128];
    __shared__ int red[256];
    int b = blockIdx.x, tid = threadIdx.x;
    int partial = 0;
    for (int i = tid; i < b; i += 256) partial += bcur[i];
    red[tid] = partial;
    if (tid < 128) {
        loff[tid] = 0;
        lcur[tid] = 0;
    }
    __syncthreads();
    for (int o = 128; o > 0; o >>= 1) {
        if (tid < o) red[tid] += red[tid + o];
        __syncthreads();
    }
    int gbase = red[0];
    int nE = bcur[b];
    if (nE > BCAP) nE = BCAP;
    const unsigned int* sb = staging + (size_t)b * BCAP;
    for (int i = tid; i < nE; i += 256) {
        unsigned int p = sb[i];
        lpk[i] = p;
        atomicAdd(&loff[p >> 25], 1);
    }
    __syncthreads();
    if (tid < 64) {
        int c0 = loff[2 * tid], c1 = loff[2 * tid + 1];
        int ps = c0 + c1;
        for (int o = 1; o < 64; o <<= 1) {
            int t = __shfl_up(ps, o);
            if (tid >= o) ps += t;
        }
        int excl = ps - (c0 + c1);
        loff[2 * tid] = excl;
        loff[2 * tid + 1] = excl + c0;
        if (tid == 63) loff[128] = ps;
    }
    __syncthreads();
    if (tid < 128) {
        int idx = b * 128 + tid;
        if (idx < N_NODES) rowptr[idx] = gbase + loff[tid];
    }
    if (tid == 0 && b == NBUCKET - 1) rowptr[N_NODES] = N_EDGES;
    for (int i = tid; i < nE; i += 256) {
        unsigned int p = lpk[i];
        int d = p >> 25;
        int pos = loff[d] + atomicAdd(&lcur[d], 1);
        lcol[pos] = (int)(p & 0x1FFFFFFu);
    }
    __syncthreads();
    for (int i = tid; i < nE; i += 256) col[gbase + i] = lcol[i];
}

// ---------------- mean aggregation: fp8 in, bf16 out, 16B lanes ----------------
// R4-R7 bracket: gather is at ~92% of the L3 line-rate ceiling (3.2M lines @
// ~97 G lines/s -> 33 µs floor). Unsigned 32-bit offsets (saddr loads), 4-deep
// col prefetch, row-major 128B rows. col loads non-temporal (stream once;
// protect L2 lines holding feature rows).

__global__ __launch_bounds__(256) void k_gather_f8(
    const unsigned char* __restrict__ hin8, const int* __restrict__ rowptr,
    const int* __restrict__ col, unsigned short* __restrict__ agg) {
    int lane = threadIdx.x & 63;
    int half = lane >> 5;
    int g = (lane >> 3) & 3;
    int t8 = lane & 7;
    int node = blockIdx.x * 8 + (threadIdx.x >> 6) * 2 + half;
    int start = rowptr[node], end = rowptr[node + 1];
    floatx2 a2[8];
#pragma unroll
    for (int j = 0; j < 8; j++) a2[j] = (floatx2){0.f, 0.f};
    const unsigned toff = (unsigned)t8 * 16u;

    auto accum = [&a2](const uint4& v) {
        const unsigned int* p = &v.x;
#pragma unroll
        for (int j = 0; j < 4; j++) {
            a2[2 * j + 0] += __builtin_amdgcn_cvt_pk_f32_fp8(p[j], false);
            a2[2 * j + 1] += __builtin_amdgcn_cvt_pk_f32_fp8(p[j], true);
        }
    };
    // unsigned-offset row load -> saddr-form global_load (32-bit voffset)
    auto rowld = [&](int idx) -> uint4 {
        return *(const uint4*)(hin8 + ((unsigned)idx * 128u + toff));
    };

    int c = start + g;
    int i1, i2, i3, i4;
    bool have = (c + 12 < end);
    if (have) {
        i1 = __builtin_nontemporal_load(col + c);
        i2 = __builtin_nontemporal_load(col + c + 4);
        i3 = __builtin_nontemporal_load(col + c + 8);
        i4 = __builtin_nontemporal_load(col + c + 12);
    }
    while (have) {
        // rows for THIS iteration use cols prefetched LAST iteration
        uint4 va = rowld(i1);
        uint4 vb = rowld(i2);
        uint4 vc = rowld(i3);
        uint4 vd = rowld(i4);
        int cn = c + 16;
        bool haven = (cn + 12 < end);
        if (haven) {  // issue next cols before waiting on the rows above
            i1 = __builtin_nontemporal_load(col + cn);
            i2 = __builtin_nontemporal_load(col + cn + 4);
            i3 = __builtin_nontemporal_load(col + cn + 8);
            i4 = __builtin_nontemporal_load(col + cn + 12);
        }
        accum(va);
        accum(vb);
        accum(vc);
        accum(vd);
        c = cn;
        have = haven;
    }
    // tail: up to 3 more edges per slot
    if (c + 4 < end) {
        int ia = __builtin_nontemporal_load(col + c);
        int ib = __builtin_nontemporal_load(col + c + 4);
        uint4 va = rowld(ia);
        uint4 vb = rowld(ib);
        accum(va);
        accum(vb);
        c += 8;
    }
    if (c < end) {
        uint4 va = rowld(__builtin_nontemporal_load(col + c));
        accum(va);
    }

    float acc[16];
#pragma unroll
    for (int j = 0; j < 8; j++) {
        acc[2 * j] = a2[j].x;
        acc[2 * j + 1] = a2[j].y;
    }
#pragma unroll
    for (int j = 0; j < 16; j++) {
        acc[j] += __shfl_xor(acc[j], 8);
        acc[j] += __shfl_xor(acc[j], 16);
    }
    if (g == 0) {
        int deg = end - start;
        float scale = 1.f / (float)(deg > 0 ? deg : 1);
        uint4 o0, o1;
        unsigned int* p0 = &o0.x;
        unsigned int* p1 = &o1.x;
#pragma unroll
        for (int j = 0; j < 4; j++) {
            p0[j] = f2bf(acc[2 * j] * scale) | (f2bf(acc[2 * j + 1] * scale) << 16);
            p1[j] = f2bf(acc[8 + 2 * j] * scale) | (f2bf(acc[8 + 2 * j + 1] * scale) << 16);
        }
        unsigned obase = (unsigned)node * 128u + (unsigned)t8 * 16u;
        *(uint4*)(agg + obase) = o0;
        *(uint4*)(agg + obase + 8u) = o1;
    }
}

// ---------------- fused linear via MFMA: 2x64-row halves per block ----------------
// W fragments load ONCE per block (vs per 64-row tile); half-B's LDS DMA
// issues right after the barrier ending half-A's LDS reads, hiding B's stage
// latency under A's register-only epilogue stores. GRID 782 (all co-resident).
// POOL variant (layer 3): no h stores; graph-mean epilogue via plain relaxed
// atomicAdd — NO fences / last-block idiom (R2: agent-scope acq_rel counter
// compiled to per-block L2 writeback+invalidate, +165 µs).

template <bool RELU, bool STORE8, bool POOL>
__global__ __launch_bounds__(256) void k_linear_mfma(
    const unsigned short* __restrict__ aggb, const unsigned short* __restrict__ hb,
    const unsigned short* __restrict__ Wt, const float* __restrict__ bl,
    unsigned short* __restrict__ hout, unsigned char* __restrict__ hout8,
    const int* __restrict__ batch, float* __restrict__ pooled,
    float* __restrict__ gcnt) {
    __shared__ unsigned char Alds[32768];  // [0,16K): agg tile, [16K,32K): h tile
    int tid = threadIdx.x;
    int w = tid >> 6, lane = tid & 63;
    int t = lane & 15, q = lane >> 4;
    size_t i0 = (size_t)blockIdx.x * 128;   // two 64-row halves

    auto stage = [&](size_t base) {
#pragma unroll
        for (int k = 0; k < 4; k++) {
            int rowc = w * 16 + k * 4 + (lane >> 4);
            int s = lane & 15;
            int c = s ^ (rowc & 15);
            gld_lds16(aggb + (base + rowc) * DIM + c * 8, Alds + (w * 16 + k * 4) * 256);
            gld_lds16(hb + (base + rowc) * DIM + c * 8,
                      Alds + 16384 + (w * 16 + k * 4) * 256);
        }
    };

    stage(i0);

    bf16x8 bfrag[2][8];
#pragma unroll
    for (int ct2 = 0; ct2 < 2; ct2++)
#pragma unroll
        for (int ks = 0; ks < 8; ks++)
            bfrag[ct2][ks] =
                *(const bf16x8*)(Wt + (size_t)(w * 32 + ct2 * 16 + t) * 256 + ks * 32 + q * 8);

    float b0 = bl[w * 32 + t];
    float b1 = bl[w * 32 + 16 + t];

    floatx4 acc[4][2];

    auto zacc = [&]() {
#pragma unroll
        for (int rt = 0; rt < 4; rt++)
#pragma unroll
            for (int c = 0; c < 2; c++) acc[rt][c] = (floatx4){0.f, 0.f, 0.f, 0.f};
    };

    auto domfma = [&]() {
#pragma unroll
        for (int ks = 0; ks < 8; ks++) {
            int half = (ks < 4) ? 0 : 16384;
            int kk = ks & 3;
            int s = ((kk * 4 + q) ^ t) * 16;
            bf16x8 af[4];
#pragma unroll
            for (int rt = 0; rt < 4; rt++)
                af[rt] = *(const bf16x8*)(Alds + half + (rt * 16 + t) * 256 + s);
#pragma unroll
            for (int rt = 0; rt < 4; rt++) {
                acc[rt][0] = __builtin_amdgcn_mfma_f32_16x16x32_bf16(af[rt], bfrag[0][ks],
                                                                     acc[rt][0], 0, 0, 0);
                acc[rt][1] = __builtin_amdgcn_mfma_f32_16x16x32_bf16(af[rt], bfrag[1][ks],
                                                                     acc[rt][1], 0, 0, 0);
            }
        }
    };

    auto epi = [&](size_t base) {
#pragma unroll
        for (int rt = 0; rt < 4; rt++) {
#pragma unroll
            for (int r = 0; r < 4; r++) {
                size_t row = base + rt * 16 + q * 4 + r;
                float v0 = acc[rt][0][r] + b0;
                float v1 = acc[rt][1][r] + b1;
                if (RELU) {
                    v0 = fmaxf(v0, 0.f);
                    v1 = fmaxf(v1, 0.f);
                }
                hout[row * DIM + w * 32 + t] = (unsigned short)f2bf(v0);
                hout[row * DIM + w * 32 + 16 + t] = (unsigned short)f2bf(v1);
                if (STORE8) {
                    unsigned int pk = __builtin_amdgcn_cvt_pk_fp8_f32(v0, v1, 0u, false);
                    hout8[row * DIM + w * 32 + t] = (unsigned char)(pk & 0xFF);
                    hout8[row * DIM + w * 32 + 16 + t] = (unsigned char)((pk >> 8) & 0xFF);
                }
            }
        }
    };

    auto pool_epi = [&](size_t base) {
        // block-uniform boundary test: batch[base] vs batch[base+63] (L2-hot)
        int g0 = batch[base];
        int lastn = (int)base + 63;
        int g63 = (lastn < N_NODES) ? batch[lastn] : -1;
        if (g0 == g63) {
            // fast path: whole 64-row half in one graph (~96%)
            float s0 = 16.f * b0, s1 = 16.f * b1;
#pragma unroll
            for (int rt = 0; rt < 4; rt++)
#pragma unroll
                for (int r = 0; r < 4; r++) {
                    s0 += acc[rt][0][r];
                    s1 += acc[rt][1][r];
                }
            s0 += __shfl_xor(s0, 16);
            s0 += __shfl_xor(s0, 32);
            s1 += __shfl_xor(s1, 16);
            s1 += __shfl_xor(s1, 32);
            if (q == 0) {
                atomicAdd(&pooled[g0 * DIM + w * 32 + t], s0);
                atomicAdd(&pooled[g0 * DIM + w * 32 + 16 + t], s1);
            }
            if (tid == 0) atomicAdd(&gcnt[g0], 64.f);
        } else {
            // slow path: graph boundary (or padding tail) inside the half
            int cur = -2;
            float s0 = 0.f, s1 = 0.f;
#pragma unroll
            for (int rt = 0; rt < 4; rt++) {
#pragma unroll
                for (int r = 0; r < 4; r++) {
                    int row = rt * 16 + q * 4 + r;
                    int n = (int)base + row;
                    int gid = (n < N_NODES) ? batch[n] : -1;
                    if (gid != cur) {
                        if (cur >= 0) {
                            atomicAdd(&pooled[cur * DIM + w * 32 + t], s0);
                            atomicAdd(&pooled[cur * DIM + w * 32 + 16 + t], s1);
                        }
                        cur = gid;
                        s0 = 0.f;
                        s1 = 0.f;
                    }
                    if (gid >= 0) {
                        s0 += acc[rt][0][r] + b0;
                        s1 += acc[rt][1][r] + b1;
                    }
                }
            }
            if (cur >= 0) {
                atomicAdd(&pooled[cur * DIM + w * 32 + t], s0);
                atomicAdd(&pooled[cur * DIM + w * 32 + 16 + t], s1);
            }
            if (tid == 0) {
                int c2 = -2, run = 0;
                for (int i2 = 0; i2 < 64; i2++) {
                    int n = (int)base + i2;
                    int gid = (n < N_NODES) ? batch[n] : -1;
                    if (gid != c2) {
                        if (c2 >= 0) atomicAdd(&gcnt[c2], (float)run);
                        c2 = gid;
                        run = 0;
                    }
                    if (gid >= 0) run++;
                }
                if (c2 >= 0) atomicAdd(&gcnt[c2], (float)run);
            }
        }
    };

    // ---- half A ----
    zacc();
    __syncthreads();          // A staged (compiler drains vmcnt before barrier)
    domfma();
    __syncthreads();          // all waves done reading LDS tile A
    stage(i0 + 64);           // issue half-B DMA; hides under A's epilogue
    if constexpr (POOL) {
        pool_epi(i0);         // i0 <= 99968 < N_NODES always
    } else {
        epi(i0);
    }
    // ---- half B ----
    zacc();
    __syncthreads();          // waits vmcnt(0): B staged (+ A stores drained)
    domfma();
    size_t i0B = i0 + 64;
    if constexpr (POOL) {
        if (i0B < N_NODES) pool_epi(i0B);  // last block's half B is pad-only
    } else {
        epi(i0B);
    }
}

__global__ void k_final(const float* __restrict__ pooled, const float* __restrict__ gcnt,
                        const float* __restrict__ Wlin, const float* __restrict__ blin,
                        float* __restrict__ out) {
    int t = threadIdx.x;  // 128 threads
    int g = t >> 1, o = t & 1;
    float sum = 0.f;
#pragma unroll 8
    for (int k = 0; k < DIM; k++) sum += pooled[g * DIM + k] * Wlin[k * 2 + o];
    float c = gcnt[g];
    out[g * 2 + o] = sum / fmaxf(c, 1.f) + blin[o];
}

// ---------------- launch ----------------

static inline size_t align_up(size_t v, size_t a) { return (v + a - 1) & ~(a - 1); }

extern "C" void kernel_launch(void* const* d_in, const int* in_sizes, int n_in,
                              void* d_out, int out_size, void* d_ws, size_t ws_size,
                              hipStream_t stream) {
    const float* x     = (const float*)d_in[0];
    const int*   ei    = (const int*)d_in[1];
    const int*   src   = ei;
    const int*   dst   = ei + N_EDGES;
    const int*   batch = (const int*)d_in[2];
    const float* Wl1 = (const float*)d_in[3];
    const float* bl1 = (const float*)d_in[4];
    const float* Wr1 = (const float*)d_in[5];
    const float* Wl2 = (const float*)d_in[6];
    const float* bl2 = (const float*)d_in[7];
    const float* Wr2 = (const float*)d_in[8];
    const float* Wl3 = (const float*)d_in[9];
    const float* bl3 = (const float*)d_in[10];
    const float* Wr3 = (const float*)d_in[11];
    const float* Wlin = (const float*)d_in[12];
    const float* blin = (const float*)d_in[13];
    float* out = (float*)d_out;

    char* p = (char*)d_ws;
    size_t off = 0;
    auto carve = [&](size_t bytes) -> void* {
        void* r = p + off;
        off = align_up(off + bytes, 256);
        return r;
    };
    int* rowptr = (int*)carve((N_NODES + 1) * sizeof(int));
    int* bcur   = (int*)carve(NBUCKET * sizeof(int));
    int* col    = (int*)carve((size_t)N_EDGES * sizeof(int));
    unsigned short* bufA = (unsigned short*)carve((size_t)M_PAD * DIM * 2);
    unsigned short* bufB = (unsigned short*)carve((size_t)M_PAD * DIM * 2);
    unsigned short* bufC = (unsigned short*)carve((size_t)M_PAD * DIM * 2);
    unsigned short* agg  = (unsigned short*)carve((size_t)M_PAD * DIM * 2);
    unsigned char*  bufA8 = (unsigned char*)carve((size_t)M_PAD * DIM);
    unsigned char*  bufB8 = (unsigned char*)carve((size_t)M_PAD * DIM);
    unsigned char*  bufC8 = (unsigned char*)carve((size_t)M_PAD * DIM);
    unsigned short* Wt1  = (unsigned short*)carve(256 * 128 * 2);
    unsigned short* Wt2  = (unsigned short*)carve(256 * 128 * 2);
    unsigned short* Wt3  = (unsigned short*)carve(256 * 128 * 2);
    float* pooled = (float*)carve((size_t)NGRAPH * DIM * sizeof(float));
    float* gcnt   = (float*)carve((size_t)NGRAPH * sizeof(float));
    // staging (12.8 MB) aliases bufB: dead after k_bsort; bufB first written
    // by layer 1's linear later on the same stream.
    unsigned int* staging = (unsigned int*)bufB;

    hipMemsetAsync(bcur, 0, NBUCKET * sizeof(int), stream);
    k_prep<<<SCAT_B + XCV_B + WCV_B + 1, 1024, 0, stream>>>(
        src, dst, bcur, staging, x, bufA, bufA8,
        Wl1, Wr1, Wt1, Wl2, Wr2, Wt2, Wl3, Wr3, Wt3, pooled, gcnt);
    k_bsort<<<NBUCKET, 256, 0, stream>>>(staging, bcur, rowptr, col);

    const int GRID_G = N_NODES / 8;  // 12500
    const int GRID_L = M_PAD / 128;  // 782 (two 64-row halves per block)

    // ---- layer 1 ----
    k_gather_f8<<<GRID_G, 256, 0, stream>>>(bufA8, rowptr, col, agg);
    k_linear_mfma<true, true, false><<<GRID_L, 256, 0, stream>>>(
        agg, bufA, Wt1, bl1, bufB, bufB8, nullptr, nullptr, nullptr);
    // ---- layer 2 ----
    k_gather_f8<<<GRID_G, 256, 0, stream>>>(bufB8, rowptr, col, agg);
    k_linear_mfma<true, true, false><<<GRID_L, 256, 0, stream>>>(
        agg, bufB, Wt2, bl2, bufC, bufC8, nullptr, nullptr, nullptr);
    // ---- layer 3: pool folded into the linear epilogue (atomics only) ----
    k_gather_f8<<<GRID_G, 256, 0, stream>>>(bufC8, rowptr, col, agg);
    k_linear_mfma<false, false, true><<<GRID_L, 256, 0, stream>>>(
        agg, bufC, Wt3, bl3, nullptr, nullptr, batch, pooled, gcnt);

    k_final<<<1, 128, 0, stream>>>(pooled, gcnt, Wlin, blin, out);
}

// Round 9
// 321.665 us; speedup vs baseline: 1.0622x; 1.0622x over previous
//
#include <hip/hip_runtime.h>

#define N_NODES 100000
#define N_EDGES 1600000
#define DIM 128
#define NGRAPH 64
#define M_PAD 100096   // 782 * 128 = 1564 * 64
#define NBUCKET 782    // ceil(100000 / 128)
#define BCAP 4096      // staging capacity per bucket (mean 2046, sigma ~45)
#define CHUNK 8192     // edges per scatter block
#define SCAT_B 196     // scatter blocks in k_prep
#define XCV_B 3125     // x-convert blocks in k_prep (12.8M floats / 4096)
#define WCV_B 24       // W-convert blocks in k_prep (98304 / 4096)

typedef __attribute__((ext_vector_type(8))) short bf16x8;
typedef __attribute__((ext_vector_type(4))) float floatx4;
typedef __attribute__((ext_vector_type(2))) float floatx2;

static __device__ __forceinline__ unsigned int f2bf(float f) {
    unsigned int u = __builtin_bit_cast(unsigned int, f);
    return (u + 0x7FFFu + ((u >> 16) & 1u)) >> 16;
}
static __device__ __forceinline__ unsigned int pk_fp8x4(float a, float b, float c, float d) {
    unsigned int r = 0;
    r = __builtin_amdgcn_cvt_pk_fp8_f32(a, b, r, false);
    r = __builtin_amdgcn_cvt_pk_fp8_f32(c, d, r, true);
    return r;
}
// async global->LDS DMA, 16B per lane; lds dest = (wave-uniform) base + lane*16
static __device__ __forceinline__ void gld_lds16(const void* g, void* l) {
    __builtin_amdgcn_global_load_lds(
        (const __attribute__((address_space(1))) unsigned int*)g,
        (__attribute__((address_space(3))) unsigned int*)l, 16, 0, 0);
}

// ---------------- fused prep: edge scatter + x->bf16+fp8 + W transpose + pool zero ----------------

__global__ __launch_bounds__(1024) void k_prep(
    const int* __restrict__ src, const int* __restrict__ dst,
    int* __restrict__ bcur, unsigned int* __restrict__ staging,
    const float* __restrict__ x, unsigned short* __restrict__ xb,
    unsigned char* __restrict__ x8,
    const float* __restrict__ Wl1, const float* __restrict__ Wr1,
    unsigned short* __restrict__ Wt1,
    const float* __restrict__ Wl2, const float* __restrict__ Wr2,
    unsigned short* __restrict__ Wt2,
    const float* __restrict__ Wl3, const float* __restrict__ Wr3,
    unsigned short* __restrict__ Wt3,
    float* __restrict__ pooled, float* __restrict__ gcnt) {
    int b = blockIdx.x;
    int tid = threadIdx.x;
    if (b < SCAT_B) {
        __shared__ int cnt[NBUCKET];
        __shared__ int gbase[NBUCKET];
        __shared__ int pos[NBUCKET];
        int e0 = b * CHUNK;
        for (int i = tid; i < NBUCKET; i += 1024) {
            cnt[i] = 0;
            pos[i] = 0;
        }
        __syncthreads();
        int s[8], d[8];
#pragma unroll
        for (int j = 0; j < 8; j++) {
            int e = e0 + j * 1024 + tid;
            if (e < N_EDGES) {
                s[j] = src[e];
                d[j] = dst[e];
                atomicAdd(&cnt[d[j] >> 7], 1);
            } else {
                d[j] = -1;
            }
        }
        __syncthreads();
        for (int i = tid; i < NBUCKET; i += 1024) {
            int c = cnt[i];
            if (c > 0) gbase[i] = atomicAdd(&bcur[i], c);
        }
        __syncthreads();
#pragma unroll
        for (int j = 0; j < 8; j++) {
            if (d[j] >= 0) {
                int bk = d[j] >> 7;
                int gp = gbase[bk] + atomicAdd(&pos[bk], 1);
                if (gp < BCAP)
                    staging[(size_t)bk * BCAP + gp] =
                        (unsigned int)s[j] | ((unsigned int)(d[j] & 127) << 25);
            }
        }
    } else if (b < SCAT_B + XCV_B) {
        size_t i = ((size_t)(b - SCAT_B) * 1024 + tid) * 4;
        float4 v = *(const float4*)(x + i);
        uint2 o;
        o.x = f2bf(v.x) | (f2bf(v.y) << 16);
        o.y = f2bf(v.z) | (f2bf(v.w) << 16);
        *(uint2*)(xb + i) = o;
        *(unsigned int*)(x8 + i) = pk_fp8x4(v.x, v.y, v.z, v.w);
    } else if (b < SCAT_B + XCV_B + WCV_B) {
        int base = (b - SCAT_B - XCV_B) * 4096 + tid * 4;
#pragma unroll
        for (int j = 0; j < 4; j++) {
            int id = base + j;                 // 0..98303
            int layer = id >> 15;
            int rem = id & 32767;
            int n = rem >> 8, k = rem & 255;
            const float* Wl = layer == 0 ? Wl1 : (layer == 1 ? Wl2 : Wl3);
            const float* Wr = layer == 0 ? Wr1 : (layer == 1 ? Wr2 : Wr3);
            unsigned short* Wt = layer == 0 ? Wt1 : (layer == 1 ? Wt2 : Wt3);
            float v = (k < 128) ? Wl[k * 128 + n] : Wr[(k - 128) * 128 + n];
            Wt[n * 256 + k] = (unsigned short)f2bf(v);
        }
    } else {
        for (int i = tid; i < NGRAPH * DIM; i += 1024) pooled[i] = 0.f;
        if (tid < NGRAPH) gcnt[tid] = 0.f;
    }
}

// ---------------- per-bucket counting sort with self-computed prefix ----------------

__global__ __launch_bounds__(256) void k_bsort(const unsigned int* __restrict__ staging,
                                               const int* __restrict__ bcur,
                                               int* __restrict__ rowptr,
                                               int* __restrict__ col) {
    __shared__ unsigned int lpk[BCAP];
    __shared__ int lcol[BCAP];
    __shared__ int loff[129];
    __shared__ int lcur[128];
    __shared__ int red[256];
    int b = blockIdx.x, tid = threadIdx.x;
    int partial = 0;
    for (int i = tid; i < b; i += 256) partial += bcur[i];
    red[tid] = partial;
    if (tid < 128) {
        loff[tid] = 0;
        lcur[tid] = 0;
    }
    __syncthreads();
    for (int o = 128; o > 0; o >>= 1) {
        if (tid < o) red[tid] += red[tid + o];
        __syncthreads();
    }
    int gbase = red[0];
    int nE = bcur[b];
    if (nE > BCAP) nE = BCAP;
    const unsigned int* sb = staging + (size_t)b * BCAP;
    for (int i = tid; i < nE; i += 256) {
        unsigned int p = sb[i];
        lpk[i] = p;
        atomicAdd(&loff[p >> 25], 1);
    }
    __syncthreads();
    if (tid < 64) {
        int c0 = loff[2 * tid], c1 = loff[2 * tid + 1];
        int ps = c0 + c1;
        for (int o = 1; o < 64; o <<= 1) {
            int t = __shfl_up(ps, o);
            if (tid >= o) ps += t;
        }
        int excl = ps - (c0 + c1);
        loff[2 * tid] = excl;
        loff[2 * tid + 1] = excl + c0;
        if (tid == 63) loff[128] = ps;
    }
    __syncthreads();
    if (tid < 128) {
        int idx = b * 128 + tid;
        if (idx < N_NODES) rowptr[idx] = gbase + loff[tid];
    }
    if (tid == 0 && b == NBUCKET - 1) rowptr[N_NODES] = N_EDGES;
    for (int i = tid; i < nE; i += 256) {
        unsigned int p = lpk[i];
        int d = p >> 25;
        int pos = loff[d] + atomicAdd(&lcur[d], 1);
        lcol[pos] = (int)(p & 0x1FFFFFFu);
    }
    __syncthreads();
    for (int i = tid; i < nE; i += 256) col[gbase + i] = lcol[i];
}

// ---------------- mean aggregation: fp8 in, bf16 out, 16B lanes ----------------
// R4-R8 bracket: gather is at ~92% of the L3 line-rate ceiling (3.2M lines @
// ~97 G lines/s -> 33 µs floor). Unsigned 32-bit offsets (saddr loads), 4-deep
// col prefetch, row-major 128B rows. Plain (cached) col loads — R8 measured
// non-temporal col loads at +4 µs/dispatch. Do NOT shard (R5/R6: 2x worse),
// do NOT fuse into MFMA tile (R1: -11%).

__global__ __launch_bounds__(256) void k_gather_f8(
    const unsigned char* __restrict__ hin8, const int* __restrict__ rowptr,
    const int* __restrict__ col, unsigned short* __restrict__ agg) {
    int lane = threadIdx.x & 63;
    int half = lane >> 5;
    int g = (lane >> 3) & 3;
    int t8 = lane & 7;
    int node = blockIdx.x * 8 + (threadIdx.x >> 6) * 2 + half;
    int start = rowptr[node], end = rowptr[node + 1];
    floatx2 a2[8];
#pragma unroll
    for (int j = 0; j < 8; j++) a2[j] = (floatx2){0.f, 0.f};
    const unsigned toff = (unsigned)t8 * 16u;

    auto accum = [&a2](const uint4& v) {
        const unsigned int* p = &v.x;
#pragma unroll
        for (int j = 0; j < 4; j++) {
            a2[2 * j + 0] += __builtin_amdgcn_cvt_pk_f32_fp8(p[j], false);
            a2[2 * j + 1] += __builtin_amdgcn_cvt_pk_f32_fp8(p[j], true);
        }
    };
    // unsigned-offset row load -> saddr-form global_load (32-bit voffset)
    auto rowld = [&](int idx) -> uint4 {
        return *(const uint4*)(hin8 + ((unsigned)idx * 128u + toff));
    };

    int c = start + g;
    int i1, i2, i3, i4;
    bool have = (c + 12 < end);
    if (have) {
        i1 = col[c];
        i2 = col[c + 4];
        i3 = col[c + 8];
        i4 = col[c + 12];
    }
    while (have) {
        // rows for THIS iteration use cols prefetched LAST iteration
        uint4 va = rowld(i1);
        uint4 vb = rowld(i2);
        uint4 vc = rowld(i3);
        uint4 vd = rowld(i4);
        int cn = c + 16;
        bool haven = (cn + 12 < end);
        if (haven) {  // issue next cols before waiting on the rows above
            i1 = col[cn];
            i2 = col[cn + 4];
            i3 = col[cn + 8];
            i4 = col[cn + 12];
        }
        accum(va);
        accum(vb);
        accum(vc);
        accum(vd);
        c = cn;
        have = haven;
    }
    // tail: up to 3 more edges per slot
    if (c + 4 < end) {
        int ia = col[c], ib = col[c + 4];
        uint4 va = rowld(ia);
        uint4 vb = rowld(ib);
        accum(va);
        accum(vb);
        c += 8;
    }
    if (c < end) {
        uint4 va = rowld(col[c]);
        accum(va);
    }

    float acc[16];
#pragma unroll
    for (int j = 0; j < 8; j++) {
        acc[2 * j] = a2[j].x;
        acc[2 * j + 1] = a2[j].y;
    }
#pragma unroll
    for (int j = 0; j < 16; j++) {
        acc[j] += __shfl_xor(acc[j], 8);
        acc[j] += __shfl_xor(acc[j], 16);
    }
    if (g == 0) {
        int deg = end - start;
        float scale = 1.f / (float)(deg > 0 ? deg : 1);
        uint4 o0, o1;
        unsigned int* p0 = &o0.x;
        unsigned int* p1 = &o1.x;
#pragma unroll
        for (int j = 0; j < 4; j++) {
            p0[j] = f2bf(acc[2 * j] * scale) | (f2bf(acc[2 * j + 1] * scale) << 16);
            p1[j] = f2bf(acc[8 + 2 * j] * scale) | (f2bf(acc[8 + 2 * j + 1] * scale) << 16);
        }
        unsigned obase = (unsigned)node * 128u + (unsigned)t8 * 16u;
        *(uint4*)(agg + obase) = o0;
        *(uint4*)(agg + obase + 8u) = o1;
    }
}

// ---------------- fused linear via MFMA, async-LDS-staged A (r10-proven) ----------------
// 64 rows/block, GRID 1564 (R8: 128-row 2-tile halved the grid to 3 blocks/CU
// and regressed — keep the latency-hiding parallelism). POOL variant (layer
// 3): no h stores; graph-mean epilogue via plain relaxed atomicAdd — NO
// fences / last-block idiom (R2: agent-scope acq_rel counter compiled to
// per-block L2 writeback+invalidate, +165 µs). k_final stays a separate
// dispatch; stream order gives visibility.

template <bool RELU, bool STORE8, bool POOL>
__global__ __launch_bounds__(256) void k_linear_mfma(
    const unsigned short* __restrict__ aggb, const unsigned short* __restrict__ hb,
    const unsigned short* __restrict__ Wt, const float* __restrict__ bl,
    unsigned short* __restrict__ hout, unsigned char* __restrict__ hout8,
    const int* __restrict__ batch, float* __restrict__ pooled,
    float* __restrict__ gcnt) {
    __shared__ unsigned char Alds[32768];  // [0,16K): agg tile, [16K,32K): h tile
    int tid = threadIdx.x;
    int w = tid >> 6, lane = tid & 63;
    int t = lane & 15, q = lane >> 4;
    size_t i0 = (size_t)blockIdx.x * 64;

    if constexpr (POOL) {
        // pad-only blocks contribute nothing (also avoids batch[] OOB read)
        if (i0 >= N_NODES) return;
    }

#pragma unroll
    for (int k = 0; k < 4; k++) {
        int rowc = w * 16 + k * 4 + (lane >> 4);
        int s = lane & 15;
        int c = s ^ (rowc & 15);
        const unsigned short* ga = aggb + (i0 + rowc) * DIM + c * 8;
        const unsigned short* gh = hb + (i0 + rowc) * DIM + c * 8;
        gld_lds16(ga, Alds + (w * 16 + k * 4) * 256);
        gld_lds16(gh, Alds + 16384 + (w * 16 + k * 4) * 256);
    }

    bf16x8 bfrag[2][8];
#pragma unroll
    for (int ct2 = 0; ct2 < 2; ct2++)
#pragma unroll
        for (int ks = 0; ks < 8; ks++)
            bfrag[ct2][ks] =
                *(const bf16x8*)(Wt + (size_t)(w * 32 + ct2 * 16 + t) * 256 + ks * 32 + q * 8);

    floatx4 acc[4][2];
#pragma unroll
    for (int rt = 0; rt < 4; rt++)
#pragma unroll
        for (int c = 0; c < 2; c++) acc[rt][c] = (floatx4){0.f, 0.f, 0.f, 0.f};

    __syncthreads();

#pragma unroll
    for (int ks = 0; ks < 8; ks++) {
        int half = (ks < 4) ? 0 : 16384;
        int kk = ks & 3;
        int s = ((kk * 4 + q) ^ t) * 16;
        bf16x8 af[4];
#pragma unroll
        for (int rt = 0; rt < 4; rt++)
            af[rt] = *(const bf16x8*)(Alds + half + (rt * 16 + t) * 256 + s);
#pragma unroll
        for (int rt = 0; rt < 4; rt++) {
            acc[rt][0] = __builtin_amdgcn_mfma_f32_16x16x32_bf16(af[rt], bfrag[0][ks],
                                                                 acc[rt][0], 0, 0, 0);
            acc[rt][1] = __builtin_amdgcn_mfma_f32_16x16x32_bf16(af[rt], bfrag[1][ks],
                                                                 acc[rt][1], 0, 0, 0);
        }
    }

    float b0 = bl[w * 32 + t];
    float b1 = bl[w * 32 + 16 + t];

    if constexpr (!POOL) {
#pragma unroll
        for (int rt = 0; rt < 4; rt++) {
#pragma unroll
            for (int r = 0; r < 4; r++) {
                size_t row = i0 + rt * 16 + q * 4 + r;
                float v0 = acc[rt][0][r] + b0;
                float v1 = acc[rt][1][r] + b1;
                if (RELU) {
                    v0 = fmaxf(v0, 0.f);
                    v1 = fmaxf(v1, 0.f);
                }
                hout[row * DIM + w * 32 + t] = (unsigned short)f2bf(v0);
                hout[row * DIM + w * 32 + 16 + t] = (unsigned short)f2bf(v1);
                if (STORE8) {
                    unsigned int pk = __builtin_amdgcn_cvt_pk_fp8_f32(v0, v1, 0u, false);
                    hout8[row * DIM + w * 32 + t] = (unsigned char)(pk & 0xFF);
                    hout8[row * DIM + w * 32 + 16 + t] = (unsigned char)((pk >> 8) & 0xFF);
                }
            }
        }
    } else {
        // block-uniform boundary test: batch[i0] vs batch[i0+63] (L2-hot)
        int g0 = batch[i0];
        int lastn = (int)i0 + 63;
        int g63 = (lastn < N_NODES) ? batch[lastn] : -1;
        if (g0 == g63) {
            // fast path: whole 64-row block in one graph (~96% of blocks)
            float s0 = 16.f * b0, s1 = 16.f * b1;
#pragma unroll
            for (int rt = 0; rt < 4; rt++)
#pragma unroll
                for (int r = 0; r < 4; r++) {
                    s0 += acc[rt][0][r];
                    s1 += acc[rt][1][r];
                }
            s0 += __shfl_xor(s0, 16);
            s0 += __shfl_xor(s0, 32);
            s1 += __shfl_xor(s1, 16);
            s1 += __shfl_xor(s1, 32);
            if (q == 0) {
                atomicAdd(&pooled[g0 * DIM + w * 32 + t], s0);
                atomicAdd(&pooled[g0 * DIM + w * 32 + 16 + t], s1);
            }
            if (tid == 0) atomicAdd(&gcnt[g0], 64.f);
        } else {
            // slow path: graph boundary (or padding tail) inside the block
            int cur = -2;
            float s0 = 0.f, s1 = 0.f;
#pragma unroll
            for (int rt = 0; rt < 4; rt++) {
#pragma unroll
                for (int r = 0; r < 4; r++) {
                    int row = rt * 16 + q * 4 + r;
                    int n = (int)i0 + row;
                    int gid = (n < N_NODES) ? batch[n] : -1;
                    if (gid != cur) {
                        if (cur >= 0) {
                            atomicAdd(&pooled[cur * DIM + w * 32 + t], s0);
                            atomicAdd(&pooled[cur * DIM + w * 32 + 16 + t], s1);
                        }
                        cur = gid;
                        s0 = 0.f;
                        s1 = 0.f;
                    }
                    if (gid >= 0) {
                        s0 += acc[rt][0][r] + b0;
                        s1 += acc[rt][1][r] + b1;
                    }
                }
            }
            if (cur >= 0) {
                atomicAdd(&pooled[cur * DIM + w * 32 + t], s0);
                atomicAdd(&pooled[cur * DIM + w * 32 + 16 + t], s1);
            }
            if (tid == 0) {
                int c2 = -2, run = 0;
                for (int i2 = 0; i2 < 64; i2++) {
                    int n = (int)i0 + i2;
                    int gid = (n < N_NODES) ? batch[n] : -1;
                    if (gid != c2) {
                        if (c2 >= 0) atomicAdd(&gcnt[c2], (float)run);
                        c2 = gid;
                        run = 0;
                    }
                    if (gid >= 0) run++;
                }
                if (c2 >= 0) atomicAdd(&gcnt[c2], (float)run);
            }
        }
    }
}

__global__ void k_final(const float* __restrict__ pooled, const float* __restrict__ gcnt,
                        const float* __restrict__ Wlin, const float* __restrict__ blin,
                        float* __restrict__ out) {
    int t = threadIdx.x;  // 128 threads
    int g = t >> 1, o = t & 1;
    float sum = 0.f;
#pragma unroll 8
    for (int k = 0; k < DIM; k++) sum += pooled[g * DIM + k] * Wlin[k * 2 + o];
    float c = gcnt[g];
    out[g * 2 + o] = sum / fmaxf(c, 1.f) + blin[o];
}

// ---------------- launch ----------------

static inline size_t align_up(size_t v, size_t a) { return (v + a - 1) & ~(a - 1); }

extern "C" void kernel_launch(void* const* d_in, const int* in_sizes, int n_in,
                              void* d_out, int out_size, void* d_ws, size_t ws_size,
                              hipStream_t stream) {
    const float* x     = (const float*)d_in[0];
    const int*   ei    = (const int*)d_in[1];
    const int*   src   = ei;
    const int*   dst   = ei + N_EDGES;
    const int*   batch = (const int*)d_in[2];
    const float* Wl1 = (const float*)d_in[3];
    const float* bl1 = (const float*)d_in[4];
    const float* Wr1 = (const float*)d_in[5];
    const float* Wl2 = (const float*)d_in[6];
    const float* bl2 = (const float*)d_in[7];
    const float* Wr2 = (const float*)d_in[8];
    const float* Wl3 = (const float*)d_in[9];
    const float* bl3 = (const float*)d_in[10];
    const float* Wr3 = (const float*)d_in[11];
    const float* Wlin = (const float*)d_in[12];
    const float* blin = (const float*)d_in[13];
    float* out = (float*)d_out;

    char* p = (char*)d_ws;
    size_t off = 0;
    auto carve = [&](size_t bytes) -> void* {
        void* r = p + off;
        off = align_up(off + bytes, 256);
        return r;
    };
    int* rowptr = (int*)carve((N_NODES + 1) * sizeof(int));
    int* bcur   = (int*)carve(NBUCKET * sizeof(int));
    int* col    = (int*)carve((size_t)N_EDGES * sizeof(int));
    unsigned short* bufA = (unsigned short*)carve((size_t)M_PAD * DIM * 2);
    unsigned short* bufB = (unsigned short*)carve((size_t)M_PAD * DIM * 2);
    unsigned short* bufC = (unsigned short*)carve((size_t)M_PAD * DIM * 2);
    unsigned short* agg  = (unsigned short*)carve((size_t)M_PAD * DIM * 2);
    unsigned char*  bufA8 = (unsigned char*)carve((size_t)M_PAD * DIM);
    unsigned char*  bufB8 = (unsigned char*)carve((size_t)M_PAD * DIM);
    unsigned char*  bufC8 = (unsigned char*)carve((size_t)M_PAD * DIM);
    unsigned short* Wt1  = (unsigned short*)carve(256 * 128 * 2);
    unsigned short* Wt2  = (unsigned short*)carve(256 * 128 * 2);
    unsigned short* Wt3  = (unsigned short*)carve(256 * 128 * 2);
    float* pooled = (float*)carve((size_t)NGRAPH * DIM * sizeof(float));
    float* gcnt   = (float*)carve((size_t)NGRAPH * sizeof(float));
    // staging (12.8 MB) aliases bufB: dead after k_bsort; bufB first written
    // by layer 1's linear later on the same stream.
    unsigned int* staging = (unsigned int*)bufB;

    hipMemsetAsync(bcur, 0, NBUCKET * sizeof(int), stream);
    k_prep<<<SCAT_B + XCV_B + WCV_B + 1, 1024, 0, stream>>>(
        src, dst, bcur, staging, x, bufA, bufA8,
        Wl1, Wr1, Wt1, Wl2, Wr2, Wt2, Wl3, Wr3, Wt3, pooled, gcnt);
    k_bsort<<<NBUCKET, 256, 0, stream>>>(staging, bcur, rowptr, col);

    const int GRID_G = N_NODES / 8;  // 12500
    const int GRID_L = M_PAD / 64;   // 1564

    // ---- layer 1 ----
    k_gather_f8<<<GRID_G, 256, 0, stream>>>(bufA8, rowptr, col, agg);
    k_linear_mfma<true, true, false><<<GRID_L, 256, 0, stream>>>(
        agg, bufA, Wt1, bl1, bufB, bufB8, nullptr, nullptr, nullptr);
    // ---- layer 2 ----
    k_gather_f8<<<GRID_G, 256, 0, stream>>>(bufB8, rowptr, col, agg);
    k_linear_mfma<true, true, false><<<GRID_L, 256, 0, stream>>>(
        agg, bufB, Wt2, bl2, bufC, bufC8, nullptr, nullptr, nullptr);
    // ---- layer 3: pool folded into the linear epilogue (atomics only) ----
    k_gather_f8<<<GRID_G, 256, 0, stream>>>(bufC8, rowptr, col, agg);
    k_linear_mfma<false, false, true><<<GRID_L, 256, 0, stream>>>(
        agg, bufC, Wt3, bl3, nullptr, nullptr, batch, pooled, gcnt);

    k_final<<<1, 128, 0, stream>>>(pooled, gcnt, Wlin, blin, out);
}